// Round 8
// baseline (256.200 us; speedup 1.0000x reference)
//
#include <hip/hip_runtime.h>
#include <hip/hip_bf16.h>
#include <math.h>

typedef float v4f __attribute__((ext_vector_type(4)));
typedef short v8s __attribute__((ext_vector_type(8)));

#define T_TOK   2048
#define DDIM    1024
#define NE      16
#define IDIM    512
#define S_ROUTED 8192
#define S_ALL   10240
#define MAXTILE 104

// ---- workspace layout (bytes) ----
#define OFF_TOPKI    0u          // 8192 ints
#define OFF_TOPKW    32768u      // 8192 floats
#define OFF_PART     65536u      // 32*16 ints
#define OFF_CBASE    69632u      // 32*16 ints
#define OFF_SEGOFF   73728u      // 18 ints
#define OFF_NTILES   74240u
#define OFF_TROW     74752u      // MAXTILE ints
#define OFF_TEND     75776u
#define OFF_TEXP     76800u
#define OFF_SLOTWT   81920u      // 8192 floats
#define OFF_S2T      114688u     // 10240 ints
#define OFF_SLOTOF   155648u     // 8192 ints
#define OFF_XBF      (1u<<20)    // 2048*1024 bf16 = 4 MB
#define OFF_H        (8u<<20)    // 10240*512 bf16 = 10 MB
#define OFF_YP       (24u<<20)   // 10240*1024 bf16 = 20 MB, ends 44 MB

__device__ __forceinline__ unsigned short f2bf(float f) {
    unsigned int u = __float_as_uint(f);
    unsigned int r = (u + 0x7fffu + ((u >> 16) & 1u)) >> 16;
    return (unsigned short)r;
}
__device__ __forceinline__ float bf2f(unsigned short s) {
    return __uint_as_float((unsigned)s << 16);
}
// packed f32x2 -> bf16x2 (RNE), one instruction
__device__ __forceinline__ unsigned cvt2(float lo, float hi) {
    unsigned r;
    asm("v_cvt_pk_bf16_f32 %0, %1, %2" : "=v"(r) : "v"(lo), "v"(hi));
    return r;
}

// ---------------- gate: fp32 logits, softmax, group-limited top-4 ----------------
__global__ __launch_bounds__(256) void gate_kernel(
    const float* __restrict__ x, const float* __restrict__ gw,
    int* __restrict__ topki, float* __restrict__ topkw,
    unsigned short* __restrict__ xbf)
{
    int t = blockIdx.x;
    int tid = threadIdx.x, lane = tid & 63, wave = tid >> 6;
    const float4* xr = (const float4*)(x + (size_t)t * DDIM);
    float4 xv[4];
#pragma unroll
    for (int j = 0; j < 4; j++) xv[j] = xr[lane + 64 * j];

    __shared__ float sc[NE];
#pragma unroll
    for (int ee = 0; ee < 4; ee++) {
        int e = wave * 4 + ee;
        const float4* wr = (const float4*)(gw + (size_t)e * DDIM);
        float acc = 0.f;
#pragma unroll
        for (int j = 0; j < 4; j++) {
            float4 w = wr[lane + 64 * j];
            acc += xv[j].x * w.x + xv[j].y * w.y + xv[j].z * w.z + xv[j].w * w.w;
        }
#pragma unroll
        for (int off = 32; off; off >>= 1) acc += __shfl_down(acc, off, 64);
        if (lane == 0) sc[e] = acc;
    }
    if (wave == 0) {
#pragma unroll
        for (int j = 0; j < 4; j++) {
            int base = 4 * (lane + 64 * j);
            uint2 p;
            p.x = (unsigned)f2bf(xv[j].x) | ((unsigned)f2bf(xv[j].y) << 16);
            p.y = (unsigned)f2bf(xv[j].z) | ((unsigned)f2bf(xv[j].w) << 16);
            *(uint2*)(xbf + (size_t)t * DDIM + base) = p;
        }
    }
    __syncthreads();
    if (tid == 0) {
        float mx = sc[0];
#pragma unroll
        for (int e = 1; e < NE; e++) mx = fmaxf(mx, sc[e]);
        float sco[NE]; float sum = 0.f;
#pragma unroll
        for (int e = 0; e < NE; e++) { sco[e] = __expf(sc[e] - mx); sum += sco[e]; }
        float inv = 1.f / sum;
#pragma unroll
        for (int e = 0; e < NE; e++) sco[e] *= inv;
        float gs[4];
#pragma unroll
        for (int g = 0; g < 4; g++) {
            float m = sco[4 * g];
            m = fmaxf(m, sco[4 * g + 1]); m = fmaxf(m, sco[4 * g + 2]); m = fmaxf(m, sco[4 * g + 3]);
            gs[g] = m;
        }
        int g0 = 0;
        for (int g = 1; g < 4; g++) if (gs[g] > gs[g0]) g0 = g;
        int g1 = -1;
        for (int g = 0; g < 4; g++) { if (g == g0) continue; if (g1 < 0 || gs[g] > gs[g1]) g1 = g; }
        float ms[NE];
#pragma unroll
        for (int e = 0; e < NE; e++) {
            int g = e >> 2;
            ms[e] = (g == g0 || g == g1) ? sco[e] : 0.0f;
        }
        bool used[NE] = {false};
        for (int k = 0; k < 4; k++) {
            int best = -1;
            for (int e = 0; e < NE; e++) {
                if (used[e]) continue;
                if (best < 0 || ms[e] > ms[best]) best = e;
            }
            used[best] = true;
            topki[t * 4 + k] = best;
            topkw[t * 4 + k] = sco[best];
        }
    }
}

// ---------------- hist ----------------
__global__ __launch_bounds__(256) void hist_kernel(
    const int* __restrict__ topki, int* __restrict__ part)
{
    __shared__ int cnt[16];
    int tid = threadIdx.x, b = blockIdx.x;
    if (tid < 16) cnt[tid] = 0;
    __syncthreads();
    int e = topki[b * 256 + tid];
    int lane = tid & 63;
#pragma unroll
    for (int e0 = 0; e0 < 16; e0++) {
        unsigned long long mask = __ballot(e == e0);
        if (lane == 0) atomicAdd(&cnt[e0], __popcll(mask));
    }
    __syncthreads();
    if (tid < 16) part[b * 16 + tid] = cnt[tid];
}

// ---------------- scan (128-row tiles) ----------------
__global__ __launch_bounds__(256) void scan_kernel(
    const int* __restrict__ part, int* __restrict__ cbase, int* __restrict__ segoff,
    int* __restrict__ trow, int* __restrict__ tend, int* __restrict__ texp,
    int* __restrict__ ntp)
{
    int tid = threadIdx.x;
    __shared__ int tot[16];
    __shared__ int so[17];
    if (tid < 16) {
        int s = 0;
        for (int b = 0; b < 32; b++) s += part[b * 16 + tid];
        tot[tid] = s;
    }
    __syncthreads();
    if (tid == 0) {
        int off = 0;
        for (int e = 0; e < 16; e++) { so[e] = off; segoff[e] = off; off += tot[e]; }
        so[16] = off; segoff[16] = off; segoff[17] = off + T_TOK;
        int nt = 0;
        for (int e = 0; e < 17; e++) {
            int n = (e < 16) ? tot[e] : T_TOK;
            int base = (e < 16) ? so[e] : S_ROUTED;
            for (int m = 0; m < n; m += 128) {
                trow[nt] = base + m; tend[nt] = base + n; texp[nt] = e; nt++;
            }
        }
        *ntp = nt;
    }
    __syncthreads();
    if (tid < 16) {
        int run = so[tid];
        for (int b = 0; b < 32; b++) { cbase[b * 16 + tid] = run; run += part[b * 16 + tid]; }
    }
}

// ---------------- assign ----------------
__global__ __launch_bounds__(256) void assign_kernel(
    const int* __restrict__ topki, const float* __restrict__ topkw,
    const int* __restrict__ cbase, int* __restrict__ s2t,
    float* __restrict__ slotwt, int* __restrict__ slotof)
{
    int b = blockIdx.x, tid = threadIdx.x;
    int i = b * 256 + tid;
    int e = topki[i];
    int lane = tid & 63, wave = tid >> 6;
    __shared__ int wcnt[4][16];
    int lrank = 0;
#pragma unroll
    for (int e0 = 0; e0 < 16; e0++) {
        unsigned long long mask = __ballot(e == e0);
        if (e == e0) lrank = __popcll(mask & ((1ull << lane) - 1ull));
        if (lane == 0) wcnt[wave][e0] = __popcll(mask);
    }
    __syncthreads();
    int pre = 0;
    for (int w = 0; w < wave; w++) pre += wcnt[w][e];
    int slot = cbase[b * 16 + e] + pre + lrank;
    int t = i >> 2;
    s2t[slot] = t;
    slotwt[slot] = topkw[i];
    slotof[i] = slot;
    if ((i & 3) == 0) s2t[S_ROUTED + t] = t;
}

// ---------------- gemm1: h = silu(X W1^T) * (X W3^T) * g ----------------
// A-direct variant: MFMA A-fragments are loaded straight from global (xbf,
// L2/L3-hot, 16B contiguous per lane) — no A LDS staging at all. This halves
// per-step LDS traffic (96->48 KB/block-step; LDS was the largest pipe,
// ~20 us floor) and reduces the loop to ONE barrier per K-step: Bs is
// double-buffered in the freed LDS; B(ki+1) regs are loaded right after the
// barrier (full compute phase of cover) and written to Bs[cur^1] after
// compute. B path otherwise identical to the verified R0 kernel.
__global__ __launch_bounds__(256, 3) void gemm1_kernel(
    const float* __restrict__ w1, const float* __restrict__ w3,
    const float* __restrict__ s1, const float* __restrict__ s3,
    const unsigned short* __restrict__ xbf,
    unsigned short* __restrict__ h, const float* __restrict__ slotwt,
    const int* __restrict__ s2t,
    const int* __restrict__ trow, const int* __restrict__ tend,
    const int* __restrict__ texp, const int* __restrict__ ntp)
{
    int bid = blockIdx.x;
    int tile = bid >> 3, ct = bid & 7;
    if (tile >= *ntp) return;
    int row0 = trow[tile], rend = tend[tile], e = texp[tile];
    int n0 = ct * 64;
    const float* B1 = (e < 16) ? (w1 + (size_t)e * 524288) : s1;
    const float* B3 = (e < 16) ? (w3 + (size_t)e * 524288) : s3;

    __shared__ __align__(16) short Bs[2][128 * 64];

    int tid = threadIdx.x;
    int lane = tid & 63, wave = tid >> 6;
    int wm = wave & 1, wn = wave >> 1;
    int mq = lane >> 4, nl = lane & 15;

    // A-fragment bases: lane handles rows wm*64 + mi*16 + nl; k-offset mq*8
    // folded into the base. Per step: a[mi] = *(v8s*)(abase[mi] + kc + ks*32).
    const unsigned short* abase[4];
#pragma unroll
    for (int mi = 0; mi < 4; mi++)
        abase[mi] = xbf + (size_t)s2t[row0 + wm * 64 + mi * 16 + nl] * DDIM + mq * 8;

    // B staging tasks: u = tid + 256j -> LDS row (u>>3) in [0,128), k-block (u&7)
    const float* bsrc[4];
    int boff[4];
#pragma unroll
    for (int j = 0; j < 4; j++) {
        int u = tid + 256 * j;
        int brow = u >> 3, bblk = u & 7;
        boff[j] = brow * 64 + ((bblk ^ (brow & 7)) * 8);
        int half = brow >> 6;
        const float* base = half ? B3 : B1;
        bsrc[j] = base + (size_t)(n0 + (brow & 63)) * DDIM + bblk * 8;
    }

    v4f acc[4][4];
#pragma unroll
    for (int i = 0; i < 4; i++)
#pragma unroll
        for (int j = 0; j < 4; j++) acc[i][j] = (v4f)0.f;

    // prologue: B(0) -> regs -> Bs[0]
    float4 br0[4], br1[4];
#pragma unroll
    for (int j = 0; j < 4; j++) {
        br0[j] = *(const float4*)(bsrc[j]);
        br1[j] = *(const float4*)(bsrc[j] + 4);
    }
#pragma unroll
    for (int j = 0; j < 4; j++) {
        uint4 p;
        p.x = cvt2(br0[j].x, br0[j].y);
        p.y = cvt2(br0[j].z, br0[j].w);
        p.z = cvt2(br1[j].x, br1[j].y);
        p.w = cvt2(br1[j].z, br1[j].w);
        *(uint4*)((short*)Bs[0] + boff[j]) = p;
    }

    int cur = 0;
    for (int ki = 0; ki < 16; ki++) {
        int kc = ki * 64;
        __syncthreads();                  // Bs[cur] writes drained; prev reads done
        if (ki < 15) {                    // B(ki+1) -> regs; full compute phase cover
#pragma unroll
            for (int j = 0; j < 4; j++) {
                br0[j] = *(const float4*)(bsrc[j] + kc + 64);
                br1[j] = *(const float4*)(bsrc[j] + kc + 68);
            }
        }
        const short* Bc = (const short*)Bs[cur];
#pragma unroll
        for (int ks = 0; ks < 2; ks++) {
            int kb = ks * 4 + mq;
            v8s a[4], b[4];
#pragma unroll
            for (int mi = 0; mi < 4; mi++)
                a[mi] = *(const v8s*)(abase[mi] + kc + ks * 32);
#pragma unroll
            for (int ni = 0; ni < 4; ni++) {
                int S = (ni >> 1) * 64 + wn * 32 + (ni & 1) * 16 + nl;  // 0,1: W1  2,3: W3
                b[ni] = *(const v8s*)(Bc + S * 64 + ((kb ^ (nl & 7)) * 8));
            }
#pragma unroll
            for (int mi = 0; mi < 4; mi++)
#pragma unroll
                for (int ni = 0; ni < 4; ni++)
                    acc[mi][ni] = __builtin_amdgcn_mfma_f32_16x16x32_bf16(a[mi], b[ni], acc[mi][ni], 0, 0, 0);
        }
        if (ki < 15) {                    // write B(ki+1) -> Bs[cur^1]
#pragma unroll
            for (int j = 0; j < 4; j++) {
                uint4 p;
                p.x = cvt2(br0[j].x, br0[j].y);
                p.y = cvt2(br0[j].z, br0[j].w);
                p.z = cvt2(br1[j].x, br1[j].y);
                p.w = cvt2(br1[j].z, br1[j].w);
                *(uint4*)((short*)Bs[cur ^ 1] + boff[j]) = p;
            }
        }
        cur ^= 1;
    }
#pragma unroll
    for (int mi = 0; mi < 4; mi++) {
#pragma unroll
        for (int r = 0; r < 4; r++) {
            int srow = row0 + wm * 64 + mi * 16 + mq * 4 + r;
            if (srow < rend) {
                float g = (srow < S_ROUTED) ? slotwt[srow] : 1.0f;
#pragma unroll
                for (int ni = 0; ni < 2; ni++) {
                    float p1 = acc[mi][ni][r], p3 = acc[mi][ni + 2][r];
                    float sig = 1.f / (1.f + __expf(-p1));
                    h[(size_t)srow * IDIM + n0 + wn * 32 + ni * 16 + nl] = f2bf(p1 * sig * p3 * g);
                }
            }
        }
    }
}

// ---------------- gemm2: yp = h @ W2^T ; same A-direct single-barrier loop ----------------
__global__ __launch_bounds__(256, 3) void gemm2_kernel(
    const float* __restrict__ w2, const float* __restrict__ s2w,
    const unsigned short* __restrict__ h, unsigned short* __restrict__ yp,
    const int* __restrict__ trow, const int* __restrict__ tend,
    const int* __restrict__ texp, const int* __restrict__ ntp)
{
    int bid = blockIdx.x;
    int tile = bid >> 3, ct = bid & 7;
    if (tile >= *ntp) return;
    int row0 = trow[tile], rend = tend[tile], e = texp[tile];
    int n0 = ct * 128;
    const float* B = ((e < 16) ? (w2 + (size_t)e * 524288) : s2w) + (size_t)n0 * IDIM;

    __shared__ __align__(16) short Bs[2][128 * 64];

    int tid = threadIdx.x;
    int lane = tid & 63, wave = tid >> 6;
    int wm = wave & 1, wn = wave >> 1;
    int mq = lane >> 4, nl = lane & 15;

    const unsigned short* abase[4];
#pragma unroll
    for (int mi = 0; mi < 4; mi++)
        abase[mi] = h + (size_t)(row0 + wm * 64 + mi * 16 + nl) * IDIM + mq * 8;

    const float* bsrc[4];
    int boff[4];
#pragma unroll
    for (int j = 0; j < 4; j++) {
        int u = tid + 256 * j;
        int brow = u >> 3, bblk = u & 7;
        boff[j] = brow * 64 + ((bblk ^ (brow & 7)) * 8);
        bsrc[j] = B + (size_t)brow * IDIM + bblk * 8;
    }

    v4f acc[4][4];
#pragma unroll
    for (int i = 0; i < 4; i++)
#pragma unroll
        for (int j = 0; j < 4; j++) acc[i][j] = (v4f)0.f;

    // prologue: B(0) -> regs -> Bs[0]
    float4 br0[4], br1[4];
#pragma unroll
    for (int j = 0; j < 4; j++) {
        br0[j] = *(const float4*)(bsrc[j]);
        br1[j] = *(const float4*)(bsrc[j] + 4);
    }
#pragma unroll
    for (int j = 0; j < 4; j++) {
        uint4 p;
        p.x = cvt2(br0[j].x, br0[j].y);
        p.y = cvt2(br0[j].z, br0[j].w);
        p.z = cvt2(br1[j].x, br1[j].y);
        p.w = cvt2(br1[j].z, br1[j].w);
        *(uint4*)((short*)Bs[0] + boff[j]) = p;
    }

    int cur = 0;
    for (int ki = 0; ki < 8; ki++) {
        int kc = ki * 64;
        __syncthreads();
        if (ki < 7) {
#pragma unroll
            for (int j = 0; j < 4; j++) {
                br0[j] = *(const float4*)(bsrc[j] + kc + 64);
                br1[j] = *(const float4*)(bsrc[j] + kc + 68);
            }
        }
        const short* Bc = (const short*)Bs[cur];
#pragma unroll
        for (int ks = 0; ks < 2; ks++) {
            int kb = ks * 4 + mq;
            v8s a[4], b[4];
#pragma unroll
            for (int mi = 0; mi < 4; mi++)
                a[mi] = *(const v8s*)(abase[mi] + kc + ks * 32);
#pragma unroll
            for (int ni = 0; ni < 4; ni++) {
                int S = wn * 64 + ni * 16 + nl;
                b[ni] = *(const v8s*)(Bc + S * 64 + ((kb ^ (nl & 7)) * 8));
            }
#pragma unroll
            for (int mi = 0; mi < 4; mi++)
#pragma unroll
                for (int ni = 0; ni < 4; ni++)
                    acc[mi][ni] = __builtin_amdgcn_mfma_f32_16x16x32_bf16(a[mi], b[ni], acc[mi][ni], 0, 0, 0);
        }
        if (ki < 7) {
#pragma unroll
            for (int j = 0; j < 4; j++) {
                uint4 p;
                p.x = cvt2(br0[j].x, br0[j].y);
                p.y = cvt2(br0[j].z, br0[j].w);
                p.z = cvt2(br1[j].x, br1[j].y);
                p.w = cvt2(br1[j].z, br1[j].w);
                *(uint4*)((short*)Bs[cur ^ 1] + boff[j]) = p;
            }
        }
        cur ^= 1;
    }
#pragma unroll
    for (int mi = 0; mi < 4; mi++) {
#pragma unroll
        for (int r = 0; r < 4; r++) {
            int srow = row0 + wm * 64 + mi * 16 + mq * 4 + r;
            if (srow < rend) {
                unsigned short* yrow = yp + ((size_t)srow << 10) + n0 + wn * 64 + nl;
#pragma unroll
                for (int ni = 0; ni < 4; ni++)
                    yrow[ni * 16] = f2bf(acc[mi][ni][r]);
            }
        }
    }
}

// ---------------- combine: out[t] = yp[shared_t] + sum of 4 routed yp rows ----------------
__global__ __launch_bounds__(256) void combine_kernel(
    const unsigned short* __restrict__ yp, const int* __restrict__ slotof,
    float* __restrict__ out)
{
    int t = blockIdx.x;
    int c = threadIdx.x * 4;
    int s0 = slotof[t * 4 + 0], s1 = slotof[t * 4 + 1];
    int s2 = slotof[t * 4 + 2], s3 = slotof[t * 4 + 3];
    ushort4 v  = *(const ushort4*)(yp + (((size_t)(S_ROUTED + t)) << 10) + c);
    ushort4 a0 = *(const ushort4*)(yp + (((size_t)s0) << 10) + c);
    ushort4 a1 = *(const ushort4*)(yp + (((size_t)s1) << 10) + c);
    ushort4 a2 = *(const ushort4*)(yp + (((size_t)s2) << 10) + c);
    ushort4 a3 = *(const ushort4*)(yp + (((size_t)s3) << 10) + c);
    float4 o;
    o.x = bf2f(v.x) + bf2f(a0.x) + bf2f(a1.x) + bf2f(a2.x) + bf2f(a3.x);
    o.y = bf2f(v.y) + bf2f(a0.y) + bf2f(a1.y) + bf2f(a2.y) + bf2f(a3.y);
    o.z = bf2f(v.z) + bf2f(a0.z) + bf2f(a1.z) + bf2f(a2.z) + bf2f(a3.z);
    o.w = bf2f(v.w) + bf2f(a0.w) + bf2f(a1.w) + bf2f(a2.w) + bf2f(a3.w);
    *(float4*)(out + (((size_t)t) << 10) + c) = o;
}

extern "C" void kernel_launch(void* const* d_in, const int* in_sizes, int n_in,
                              void* d_out, int out_size, void* d_ws, size_t ws_size,
                              hipStream_t stream) {
    const float* x    = (const float*)d_in[0];
    const float* gw   = (const float*)d_in[1];
    const float* w1   = (const float*)d_in[2];
    const float* w2   = (const float*)d_in[3];
    const float* w3   = (const float*)d_in[4];
    const float* wsh1 = (const float*)d_in[5];
    const float* wsh2 = (const float*)d_in[6];
    const float* wsh3 = (const float*)d_in[7];
    float* out = (float*)d_out;

    char* ws = (char*)d_ws;
    int*   topki  = (int*)(ws + OFF_TOPKI);
    float* topkw  = (float*)(ws + OFF_TOPKW);
    int*   part   = (int*)(ws + OFF_PART);
    int*   cbase  = (int*)(ws + OFF_CBASE);
    int*   segoff = (int*)(ws + OFF_SEGOFF);
    int*   ntp    = (int*)(ws + OFF_NTILES);
    int*   trow   = (int*)(ws + OFF_TROW);
    int*   tend   = (int*)(ws + OFF_TEND);
    int*   texp   = (int*)(ws + OFF_TEXP);
    float* slotwt = (float*)(ws + OFF_SLOTWT);
    int*   s2t    = (int*)(ws + OFF_S2T);
    int*   slotof = (int*)(ws + OFF_SLOTOF);
    unsigned short* xbf = (unsigned short*)(ws + OFF_XBF);
    unsigned short* h   = (unsigned short*)(ws + OFF_H);
    unsigned short* yp  = (unsigned short*)(ws + OFF_YP);

    gate_kernel<<<T_TOK, 256, 0, stream>>>(x, gw, topki, topkw, xbf);
    hist_kernel<<<32, 256, 0, stream>>>(topki, part);
    scan_kernel<<<1, 256, 0, stream>>>(part, cbase, segoff, trow, tend, texp, ntp);
    assign_kernel<<<32, 256, 0, stream>>>(topki, topkw, cbase, s2t, slotwt, slotof);
    gemm1_kernel<<<MAXTILE * 8, 256, 0, stream>>>(w1, w3, wsh1, wsh3, xbf, h, slotwt, s2t,
                                                  trow, tend, texp, ntp);
    gemm2_kernel<<<MAXTILE * 8, 256, 0, stream>>>(w2, wsh2, h, yp, trow, tend, texp, ntp);
    combine_kernel<<<T_TOK, 256, 0, stream>>>(yp, slotof, out);
}

// Round 9
// 242.360 us; speedup vs baseline: 1.0571x; 1.0571x over previous
//
#include <hip/hip_runtime.h>
#include <hip/hip_bf16.h>
#include <math.h>

typedef float v4f __attribute__((ext_vector_type(4)));
typedef short v8s __attribute__((ext_vector_type(8)));

#define T_TOK   2048
#define DDIM    1024
#define NE      16
#define IDIM    512
#define S_ROUTED 8192
#define S_ALL   10240
#define MAXTILE 104

// ---- workspace layout (bytes) ----
#define OFF_TOPKI    0u          // 8192 ints
#define OFF_TOPKW    32768u      // 8192 floats
#define OFF_PART     65536u      // 32*16 ints
#define OFF_CBASE    69632u      // 32*16 ints
#define OFF_SEGOFF   73728u      // 18 ints
#define OFF_NTILES   74240u
#define OFF_TROW     74752u      // MAXTILE ints
#define OFF_TEND     75776u
#define OFF_TEXP     76800u
#define OFF_SLOTWT   81920u      // 8192 floats
#define OFF_S2T      114688u     // 10240 ints
#define OFF_SLOTOF   155648u     // 8192 ints
#define OFF_XBF      (1u<<20)    // 2048*1024 bf16 = 4 MB, ends 5 MB
#define OFF_H        (8u<<20)    // 10240*512 bf16 = 10 MB, ends 18 MB
#define OFF_YP       (24u<<20)   // 10240*1024 bf16 = 20 MB, ends 44 MB
// bf16 weights (written by wconv before gemm1; w1/w3 dead after gemm1, so
// yp [24,44) MB legally overlays them during gemm2)
#define OFF_W1BF     (24u<<20)   // 16 MB
#define OFF_W3BF     (40u<<20)   // 16 MB
#define OFF_W2BF     (56u<<20)   // 16 MB (live through gemm2; no overlap w/ yp? yp ends 44 ✓)
#define OFF_S1BF     (72u<<20)   // 1 MB
#define OFF_S3BF     (73u<<20)   // 1 MB
#define OFF_S2BF     (74u<<20)   // 1 MB, ends 75 MB

__device__ __forceinline__ unsigned short f2bf(float f) {
    unsigned int u = __float_as_uint(f);
    unsigned int r = (u + 0x7fffu + ((u >> 16) & 1u)) >> 16;
    return (unsigned short)r;
}
__device__ __forceinline__ float bf2f(unsigned short s) {
    return __uint_as_float((unsigned)s << 16);
}
// packed f32x2 -> bf16x2 (RNE), one instruction
__device__ __forceinline__ unsigned cvt2(float lo, float hi) {
    unsigned r;
    asm("v_cvt_pk_bf16_f32 %0, %1, %2" : "=v"(r) : "v"(lo), "v"(hi));
    return r;
}

// async global->LDS, 16B/lane, LDS dest = uniform base + lane*16
#define GLL16(gp, lp) __builtin_amdgcn_global_load_lds( \
    (__attribute__((address_space(1))) void*)(gp), \
    (__attribute__((address_space(3))) void*)(lp), 16, 0, 0)

// ---------------- wconv: fp32 weights -> bf16 (once per launch) ----------------
__global__ __launch_bounds__(256) void wconv_kernel(
    const float* __restrict__ w1, const float* __restrict__ w3,
    const float* __restrict__ w2, const float* __restrict__ s1,
    const float* __restrict__ s3, const float* __restrict__ s2,
    unsigned short* __restrict__ o1, unsigned short* __restrict__ o3,
    unsigned short* __restrict__ o2, unsigned short* __restrict__ os1,
    unsigned short* __restrict__ os3, unsigned short* __restrict__ os2)
{
    const int BIG = 1048576;   // 16*512*1024/8 float8-tasks
    const int SMALL = 65536;   // 512*1024/8
    const int total = 3 * BIG + 3 * SMALL;
    for (int i = blockIdx.x * 256 + threadIdx.x; i < total; i += gridDim.x * 256) {
        const float* s; unsigned short* d; int off;
        if (i < BIG)            { s = w1; d = o1;  off = i; }
        else if (i < 2 * BIG)   { s = w3; d = o3;  off = i - BIG; }
        else if (i < 3 * BIG)   { s = w2; d = o2;  off = i - 2 * BIG; }
        else {
            int k = i - 3 * BIG;
            if (k < SMALL)          { s = s1; d = os1; off = k; }
            else if (k < 2 * SMALL) { s = s3; d = os3; off = k - SMALL; }
            else                    { s = s2; d = os2; off = k - 2 * SMALL; }
        }
        float4 a = *(const float4*)(s + (size_t)off * 8);
        float4 b = *(const float4*)(s + (size_t)off * 8 + 4);
        uint4 p;
        p.x = cvt2(a.x, a.y); p.y = cvt2(a.z, a.w);
        p.z = cvt2(b.x, b.y); p.w = cvt2(b.z, b.w);
        *(uint4*)(d + (size_t)off * 8) = p;
    }
}

// ---------------- gate: fp32 logits, softmax, group-limited top-4 ----------------
__global__ __launch_bounds__(256) void gate_kernel(
    const float* __restrict__ x, const float* __restrict__ gw,
    int* __restrict__ topki, float* __restrict__ topkw,
    unsigned short* __restrict__ xbf)
{
    int t = blockIdx.x;
    int tid = threadIdx.x, lane = tid & 63, wave = tid >> 6;
    const float4* xr = (const float4*)(x + (size_t)t * DDIM);
    float4 xv[4];
#pragma unroll
    for (int j = 0; j < 4; j++) xv[j] = xr[lane + 64 * j];

    __shared__ float sc[NE];
#pragma unroll
    for (int ee = 0; ee < 4; ee++) {
        int e = wave * 4 + ee;
        const float4* wr = (const float4*)(gw + (size_t)e * DDIM);
        float acc = 0.f;
#pragma unroll
        for (int j = 0; j < 4; j++) {
            float4 w = wr[lane + 64 * j];
            acc += xv[j].x * w.x + xv[j].y * w.y + xv[j].z * w.z + xv[j].w * w.w;
        }
#pragma unroll
        for (int off = 32; off; off >>= 1) acc += __shfl_down(acc, off, 64);
        if (lane == 0) sc[e] = acc;
    }
    if (wave == 0) {
#pragma unroll
        for (int j = 0; j < 4; j++) {
            int base = 4 * (lane + 64 * j);
            uint2 p;
            p.x = (unsigned)f2bf(xv[j].x) | ((unsigned)f2bf(xv[j].y) << 16);
            p.y = (unsigned)f2bf(xv[j].z) | ((unsigned)f2bf(xv[j].w) << 16);
            *(uint2*)(xbf + (size_t)t * DDIM + base) = p;
        }
    }
    __syncthreads();
    if (tid == 0) {
        float mx = sc[0];
#pragma unroll
        for (int e = 1; e < NE; e++) mx = fmaxf(mx, sc[e]);
        float sco[NE]; float sum = 0.f;
#pragma unroll
        for (int e = 0; e < NE; e++) { sco[e] = __expf(sc[e] - mx); sum += sco[e]; }
        float inv = 1.f / sum;
#pragma unroll
        for (int e = 0; e < NE; e++) sco[e] *= inv;
        float gs[4];
#pragma unroll
        for (int g = 0; g < 4; g++) {
            float m = sco[4 * g];
            m = fmaxf(m, sco[4 * g + 1]); m = fmaxf(m, sco[4 * g + 2]); m = fmaxf(m, sco[4 * g + 3]);
            gs[g] = m;
        }
        int g0 = 0;
        for (int g = 1; g < 4; g++) if (gs[g] > gs[g0]) g0 = g;
        int g1 = -1;
        for (int g = 0; g < 4; g++) { if (g == g0) continue; if (g1 < 0 || gs[g] > gs[g1]) g1 = g; }
        float ms[NE];
#pragma unroll
        for (int e = 0; e < NE; e++) {
            int g = e >> 2;
            ms[e] = (g == g0 || g == g1) ? sco[e] : 0.0f;
        }
        bool used[NE] = {false};
        for (int k = 0; k < 4; k++) {
            int best = -1;
            for (int e = 0; e < NE; e++) {
                if (used[e]) continue;
                if (best < 0 || ms[e] > ms[best]) best = e;
            }
            used[best] = true;
            topki[t * 4 + k] = best;
            topkw[t * 4 + k] = sco[best];
        }
    }
}

// ---------------- hist ----------------
__global__ __launch_bounds__(256) void hist_kernel(
    const int* __restrict__ topki, int* __restrict__ part)
{
    __shared__ int cnt[16];
    int tid = threadIdx.x, b = blockIdx.x;
    if (tid < 16) cnt[tid] = 0;
    __syncthreads();
    int e = topki[b * 256 + tid];
    int lane = tid & 63;
#pragma unroll
    for (int e0 = 0; e0 < 16; e0++) {
        unsigned long long mask = __ballot(e == e0);
        if (lane == 0) atomicAdd(&cnt[e0], __popcll(mask));
    }
    __syncthreads();
    if (tid < 16) part[b * 16 + tid] = cnt[tid];
}

// ---------------- scan (128-row tiles) ----------------
__global__ __launch_bounds__(256) void scan_kernel(
    const int* __restrict__ part, int* __restrict__ cbase, int* __restrict__ segoff,
    int* __restrict__ trow, int* __restrict__ tend, int* __restrict__ texp,
    int* __restrict__ ntp)
{
    int tid = threadIdx.x;
    __shared__ int tot[16];
    __shared__ int so[17];
    if (tid < 16) {
        int s = 0;
        for (int b = 0; b < 32; b++) s += part[b * 16 + tid];
        tot[tid] = s;
    }
    __syncthreads();
    if (tid == 0) {
        int off = 0;
        for (int e = 0; e < 16; e++) { so[e] = off; segoff[e] = off; off += tot[e]; }
        so[16] = off; segoff[16] = off; segoff[17] = off + T_TOK;
        int nt = 0;
        for (int e = 0; e < 17; e++) {
            int n = (e < 16) ? tot[e] : T_TOK;
            int base = (e < 16) ? so[e] : S_ROUTED;
            for (int m = 0; m < n; m += 128) {
                trow[nt] = base + m; tend[nt] = base + n; texp[nt] = e; nt++;
            }
        }
        *ntp = nt;
    }
    __syncthreads();
    if (tid < 16) {
        int run = so[tid];
        for (int b = 0; b < 32; b++) { cbase[b * 16 + tid] = run; run += part[b * 16 + tid]; }
    }
}

// ---------------- assign ----------------
__global__ __launch_bounds__(256) void assign_kernel(
    const int* __restrict__ topki, const float* __restrict__ topkw,
    const int* __restrict__ cbase, int* __restrict__ s2t,
    float* __restrict__ slotwt, int* __restrict__ slotof)
{
    int b = blockIdx.x, tid = threadIdx.x;
    int i = b * 256 + tid;
    int e = topki[i];
    int lane = tid & 63, wave = tid >> 6;
    __shared__ int wcnt[4][16];
    int lrank = 0;
#pragma unroll
    for (int e0 = 0; e0 < 16; e0++) {
        unsigned long long mask = __ballot(e == e0);
        if (e == e0) lrank = __popcll(mask & ((1ull << lane) - 1ull));
        if (lane == 0) wcnt[wave][e0] = __popcll(mask);
    }
    __syncthreads();
    int pre = 0;
    for (int w = 0; w < wave; w++) pre += wcnt[w][e];
    int slot = cbase[b * 16 + e] + pre + lrank;
    int t = i >> 2;
    s2t[slot] = t;
    slotwt[slot] = topkw[i];
    slotof[i] = slot;
    if ((i & 3) == 0) s2t[S_ROUTED + t] = t;
}

// ---------------- gemm1: h = silu(X W1^T) * (X W3^T) * g ----------------
// All-DMA counted-vmcnt pipeline (T3+T4): both A (xbf) and B (bf16 weights)
// stage via GLL16 with PRE-SWIZZLED global sources (m173) into double-buffered
// LDS. Zero reg-staging, zero ds_writes -> no spill risk (R2/R6 failure mode
// eliminated). Each wave issues exactly 8 GLL16 per tile; per step:
//   s_waitcnt vmcnt(8)  (tile ki resident, tile ki+1 still in flight)
//   s_barrier ; 32 MFMA on buf[ki&1] ; s_barrier ; issue tile ki+2 -> buf[ki&1]
// B-load latency gets ~2 full K-steps of cover ACROSS barriers.
#define G1_ISSUE(T, BUF) do {                                                  \
    _Pragma("unroll")                                                          \
    for (int j = 0; j < 4; j++)                                                \
        GLL16(asrc[j] + (T) * 64, (short*)As[BUF] + wave * 2048 + j * 512);    \
    _Pragma("unroll")                                                          \
    for (int j = 0; j < 4; j++)                                                \
        GLL16(bsrc[j] + (T) * 64, (short*)Bs[BUF] + wave * 512 + j * 2048);    \
} while (0)

#define G1_COMP(BUF) do {                                                      \
    const short* Ac = (const short*)As[BUF];                                   \
    const short* Bc = (const short*)Bs[BUF];                                   \
    _Pragma("unroll")                                                          \
    for (int ks = 0; ks < 2; ks++) {                                           \
        int kb = ks * 4 + mq;                                                  \
        v8s a[4], b[4];                                                        \
        _Pragma("unroll")                                                      \
        for (int mi = 0; mi < 4; mi++) {                                       \
            int R = wm * 64 + mi * 16 + nl;                                    \
            a[mi] = *(const v8s*)(Ac + R * 64 + ((kb ^ (nl & 7)) * 8));        \
        }                                                                      \
        _Pragma("unroll")                                                      \
        for (int ni = 0; ni < 4; ni++) {                                       \
            int S = (ni >> 1) * 64 + wn * 32 + (ni & 1) * 16 + nl;             \
            b[ni] = *(const v8s*)(Bc + S * 64 + ((kb ^ (nl & 7)) * 8));        \
        }                                                                      \
        _Pragma("unroll")                                                      \
        for (int mi = 0; mi < 4; mi++)                                         \
            _Pragma("unroll")                                                  \
            for (int ni = 0; ni < 4; ni++)                                     \
                acc[mi][ni] = __builtin_amdgcn_mfma_f32_16x16x32_bf16(         \
                    a[mi], b[ni], acc[mi][ni], 0, 0, 0);                       \
    }                                                                          \
} while (0)

__global__ __launch_bounds__(256, 2) void gemm1_kernel(
    const unsigned short* __restrict__ w1bf, const unsigned short* __restrict__ w3bf,
    const unsigned short* __restrict__ s1bf, const unsigned short* __restrict__ s3bf,
    const unsigned short* __restrict__ xbf,
    unsigned short* __restrict__ h, const float* __restrict__ slotwt,
    const int* __restrict__ s2t,
    const int* __restrict__ trow, const int* __restrict__ tend,
    const int* __restrict__ texp, const int* __restrict__ ntp)
{
    int bid = blockIdx.x;
    int tile = bid >> 3, ct = bid & 7;
    if (tile >= *ntp) return;
    int row0 = trow[tile], rend = tend[tile], e = texp[tile];
    int n0 = ct * 64;
    const unsigned short* B1 = (e < 16) ? (w1bf + (size_t)e * 524288) : s1bf;
    const unsigned short* B3 = (e < 16) ? (w3bf + (size_t)e * 524288) : s3bf;

    __shared__ __align__(16) short As[2][128 * 64];
    __shared__ __align__(16) short Bs[2][128 * 64];

    int tid = threadIdx.x;
    int lane = tid & 63, wave = tid >> 6;
    int wm = wave & 1, wn = wave >> 1;
    int mq = lane >> 4, nl = lane & 15;
    int rr = lane >> 3, s7 = lane & 7;
    int swz = (s7 ^ rr) * 8;           // pre-swizzled k-block offset (elems)

    // A: rows wave*32 + j*8 + rr (via s2t); LDS rows linear per wave
    const unsigned short* asrc[4];
#pragma unroll
    for (int j = 0; j < 4; j++)
        asrc[j] = xbf + (size_t)s2t[row0 + wave * 32 + j * 8 + rr] * DDIM + swz;

    // B: rows R = wave*8 + j*32 + rr ; R<64 -> W1 col n0+R, R>=64 -> W3 col n0+(R&63)
    const unsigned short* bsrc[4];
#pragma unroll
    for (int j = 0; j < 4; j++) {
        int R = wave * 8 + j * 32 + rr;
        const unsigned short* base = (R >> 6) ? B3 : B1;
        bsrc[j] = base + (size_t)(n0 + (R & 63)) * DDIM + swz;
    }

    v4f acc[4][4];
#pragma unroll
    for (int i = 0; i < 4; i++)
#pragma unroll
        for (int j = 0; j < 4; j++) acc[i][j] = (v4f)0.f;

    G1_ISSUE(0, 0);
    G1_ISSUE(1, 1);
    for (int ki = 0; ki < 15; ki++) {
        asm volatile("s_waitcnt vmcnt(8)" ::: "memory");
        __builtin_amdgcn_s_barrier();
        G1_COMP(ki & 1);
        __builtin_amdgcn_s_barrier();
        if (ki < 14) G1_ISSUE(ki + 2, ki & 1);
    }
    asm volatile("s_waitcnt vmcnt(0)" ::: "memory");
    __builtin_amdgcn_s_barrier();
    G1_COMP(1);

#pragma unroll
    for (int mi = 0; mi < 4; mi++) {
#pragma unroll
        for (int r = 0; r < 4; r++) {
            int srow = row0 + wm * 64 + mi * 16 + mq * 4 + r;
            if (srow < rend) {
                float g = (srow < S_ROUTED) ? slotwt[srow] : 1.0f;
#pragma unroll
                for (int ni = 0; ni < 2; ni++) {
                    float p1 = acc[mi][ni][r], p3 = acc[mi][ni + 2][r];
                    float sig = 1.f / (1.f + __expf(-p1));
                    h[(size_t)srow * IDIM + n0 + wn * 32 + ni * 16 + nl] = f2bf(p1 * sig * p3 * g);
                }
            }
        }
    }
}

// ---------------- gemm2: yp = h @ W2^T ; same all-DMA counted pipeline ----------------
#define G2_ISSUE(T, BUF) do {                                                  \
    _Pragma("unroll")                                                          \
    for (int j = 0; j < 4; j++)                                                \
        GLL16(asrc[j] + (T) * 64, (short*)As[BUF] + wave * 2048 + j * 512);    \
    _Pragma("unroll")                                                          \
    for (int j = 0; j < 4; j++)                                                \
        GLL16(bsrc[j] + (T) * 64, (short*)Bs[BUF] + wave * 512 + j * 2048);    \
} while (0)

#define G2_COMP(BUF) do {                                                      \
    const short* Ac = (const short*)As[BUF];                                   \
    const short* Bc = (const short*)Bs[BUF];                                   \
    _Pragma("unroll")                                                          \
    for (int ks = 0; ks < 2; ks++) {                                           \
        int kb = ks * 4 + mq;                                                  \
        v8s a[4], b[4];                                                        \
        _Pragma("unroll")                                                      \
        for (int mi = 0; mi < 4; mi++) {                                       \
            int R = wm * 64 + mi * 16 + nl;                                    \
            a[mi] = *(const v8s*)(Ac + R * 64 + ((kb ^ (nl & 7)) * 8));        \
        }                                                                      \
        _Pragma("unroll")                                                      \
        for (int ni = 0; ni < 4; ni++) {                                       \
            int S = wn * 64 + ni * 16 + nl;                                    \
            b[ni] = *(const v8s*)(Bc + S * 64 + ((kb ^ (nl & 7)) * 8));        \
        }                                                                      \
        _Pragma("unroll")                                                      \
        for (int mi = 0; mi < 4; mi++)                                         \
            _Pragma("unroll")                                                  \
            for (int ni = 0; ni < 4; ni++)                                     \
                acc[mi][ni] = __builtin_amdgcn_mfma_f32_16x16x32_bf16(         \
                    a[mi], b[ni], acc[mi][ni], 0, 0, 0);                       \
    }                                                                          \
} while (0)

__global__ __launch_bounds__(256, 2) void gemm2_kernel(
    const unsigned short* __restrict__ w2bf, const unsigned short* __restrict__ s2bf,
    const unsigned short* __restrict__ h, unsigned short* __restrict__ yp,
    const int* __restrict__ trow, const int* __restrict__ tend,
    const int* __restrict__ texp, const int* __restrict__ ntp)
{
    int bid = blockIdx.x;
    int tile = bid >> 3, ct = bid & 7;
    if (tile >= *ntp) return;
    int row0 = trow[tile], rend = tend[tile], e = texp[tile];
    int n0 = ct * 128;
    const unsigned short* B = ((e < 16) ? (w2bf + (size_t)e * 524288) : s2bf) + (size_t)n0 * IDIM;

    __shared__ __align__(16) short As[2][128 * 64];
    __shared__ __align__(16) short Bs[2][128 * 64];

    int tid = threadIdx.x;
    int lane = tid & 63, wave = tid >> 6;
    int wm = wave & 1, wn = wave >> 1;
    int mq = lane >> 4, nl = lane & 15;
    int rr = lane >> 3, s7 = lane & 7;
    int swz = (s7 ^ rr) * 8;

    const unsigned short* asrc[4];
#pragma unroll
    for (int j = 0; j < 4; j++)
        asrc[j] = h + (size_t)(row0 + wave * 32 + j * 8 + rr) * IDIM + swz;

    const unsigned short* bsrc[4];
#pragma unroll
    for (int j = 0; j < 4; j++) {
        int R = wave * 8 + j * 32 + rr;
        bsrc[j] = B + (size_t)R * IDIM + swz;
    }

    v4f acc[4][4];
#pragma unroll
    for (int i = 0; i < 4; i++)
#pragma unroll
        for (int j = 0; j < 4; j++) acc[i][j] = (v4f)0.f;

    G2_ISSUE(0, 0);
    G2_ISSUE(1, 1);
    for (int ki = 0; ki < 7; ki++) {
        asm volatile("s_waitcnt vmcnt(8)" ::: "memory");
        __builtin_amdgcn_s_barrier();
        G2_COMP(ki & 1);
        __builtin_amdgcn_s_barrier();
        if (ki < 6) G2_ISSUE(ki + 2, ki & 1);
    }
    asm volatile("s_waitcnt vmcnt(0)" ::: "memory");
    __builtin_amdgcn_s_barrier();
    G2_COMP(1);

#pragma unroll
    for (int mi = 0; mi < 4; mi++) {
#pragma unroll
        for (int r = 0; r < 4; r++) {
            int srow = row0 + wm * 64 + mi * 16 + mq * 4 + r;
            if (srow < rend) {
                unsigned short* yrow = yp + ((size_t)srow << 10) + n0 + wn * 64 + nl;
#pragma unroll
                for (int ni = 0; ni < 4; ni++)
                    yrow[ni * 16] = f2bf(acc[mi][ni][r]);
            }
        }
    }
}

// ---------------- combine: out[t] = yp[shared_t] + sum of 4 routed yp rows ----------------
__global__ __launch_bounds__(256) void combine_kernel(
    const unsigned short* __restrict__ yp, const int* __restrict__ slotof,
    float* __restrict__ out)
{
    int t = blockIdx.x;
    int c = threadIdx.x * 4;
    int s0 = slotof[t * 4 + 0], s1 = slotof[t * 4 + 1];
    int s2 = slotof[t * 4 + 2], s3 = slotof[t * 4 + 3];
    ushort4 v  = *(const ushort4*)(yp + (((size_t)(S_ROUTED + t)) << 10) + c);
    ushort4 a0 = *(const ushort4*)(yp + (((size_t)s0) << 10) + c);
    ushort4 a1 = *(const ushort4*)(yp + (((size_t)s1) << 10) + c);
    ushort4 a2 = *(const ushort4*)(yp + (((size_t)s2) << 10) + c);
    ushort4 a3 = *(const ushort4*)(yp + (((size_t)s3) << 10) + c);
    float4 o;
    o.x = bf2f(v.x) + bf2f(a0.x) + bf2f(a1.x) + bf2f(a2.x) + bf2f(a3.x);
    o.y = bf2f(v.y) + bf2f(a0.y) + bf2f(a1.y) + bf2f(a2.y) + bf2f(a3.y);
    o.z = bf2f(v.z) + bf2f(a0.z) + bf2f(a1.z) + bf2f(a2.z) + bf2f(a3.z);
    o.w = bf2f(v.w) + bf2f(a0.w) + bf2f(a1.w) + bf2f(a2.w) + bf2f(a3.w);
    *(float4*)(out + (((size_t)t) << 10) + c) = o;
}

extern "C" void kernel_launch(void* const* d_in, const int* in_sizes, int n_in,
                              void* d_out, int out_size, void* d_ws, size_t ws_size,
                              hipStream_t stream) {
    const float* x    = (const float*)d_in[0];
    const float* gw   = (const float*)d_in[1];
    const float* w1   = (const float*)d_in[2];
    const float* w2   = (const float*)d_in[3];
    const float* w3   = (const float*)d_in[4];
    const float* wsh1 = (const float*)d_in[5];
    const float* wsh2 = (const float*)d_in[6];
    const float* wsh3 = (const float*)d_in[7];
    float* out = (float*)d_out;

    char* ws = (char*)d_ws;
    int*   topki  = (int*)(ws + OFF_TOPKI);
    float* topkw  = (float*)(ws + OFF_TOPKW);
    int*   part   = (int*)(ws + OFF_PART);
    int*   cbase  = (int*)(ws + OFF_CBASE);
    int*   segoff = (int*)(ws + OFF_SEGOFF);
    int*   ntp    = (int*)(ws + OFF_NTILES);
    int*   trow   = (int*)(ws + OFF_TROW);
    int*   tend   = (int*)(ws + OFF_TEND);
    int*   texp   = (int*)(ws + OFF_TEXP);
    float* slotwt = (float*)(ws + OFF_SLOTWT);
    int*   s2t    = (int*)(ws + OFF_S2T);
    int*   slotof = (int*)(ws + OFF_SLOTOF);
    unsigned short* xbf  = (unsigned short*)(ws + OFF_XBF);
    unsigned short* h    = (unsigned short*)(ws + OFF_H);
    unsigned short* yp   = (unsigned short*)(ws + OFF_YP);
    unsigned short* w1bf = (unsigned short*)(ws + OFF_W1BF);
    unsigned short* w3bf = (unsigned short*)(ws + OFF_W3BF);
    unsigned short* w2bf = (unsigned short*)(ws + OFF_W2BF);
    unsigned short* s1bf = (unsigned short*)(ws + OFF_S1BF);
    unsigned short* s3bf = (unsigned short*)(ws + OFF_S3BF);
    unsigned short* s2bf = (unsigned short*)(ws + OFF_S2BF);

    wconv_kernel<<<4096, 256, 0, stream>>>(w1, w3, w2, wsh1, wsh3, wsh2,
                                           w1bf, w3bf, w2bf, s1bf, s3bf, s2bf);
    gate_kernel<<<T_TOK, 256, 0, stream>>>(x, gw, topki, topkw, xbf);
    hist_kernel<<<32, 256, 0, stream>>>(topki, part);
    scan_kernel<<<1, 256, 0, stream>>>(part, cbase, segoff, trow, tend, texp, ntp);
    assign_kernel<<<32, 256, 0, stream>>>(topki, topkw, cbase, s2t, slotwt, slotof);
    gemm1_kernel<<<MAXTILE * 8, 256, 0, stream>>>(w1bf, w3bf, s1bf, s3bf, xbf, h, slotwt, s2t,
                                                  trow, tend, texp, ntp);
    gemm2_kernel<<<MAXTILE * 8, 256, 0, stream>>>(w2bf, s2bf, h, yp, trow, tend, texp, ntp);
    combine_kernel<<<T_TOK, 256, 0, stream>>>(yp, slotof, out);
}